// Round 16
// baseline (100.500 us; speedup 1.0000x reference)
//
#include <hip/hip_runtime.h>

#define B_    8
#define CIN_  64
#define COUT_ 64
#define H_    256
#define W_    256
#define HW_   65536

typedef __attribute__((ext_vector_type(8)))  short short8;    // 8 bf16 = 4 VGPRs
typedef __attribute__((ext_vector_type(16))) float f32x16;
typedef __attribute__((ext_vector_type(4)))  unsigned uint32x4;  // native vec for nt-store

static __device__ __forceinline__ unsigned short f2bf(float f) {
    union { float f; unsigned u; } v; v.f = f;
    unsigned r = (v.u + 0x7FFFu + ((v.u >> 16) & 1u)) >> 16;  // RNE
    return (unsigned short)r;
}

// async global->LDS, 16B per lane. LDS dest = wave-uniform base + lane*16.
static __device__ __forceinline__ void gload16(void* lds, const void* g) {
    __builtin_amdgcn_global_load_lds(
        (const __attribute__((address_space(1))) unsigned int*)g,
        (__attribute__((address_space(3))) unsigned int*)lds, 16, 0, 0);
}

// inline-asm barrier: also a compiler memory fence.
static __device__ __forceinline__ void bar() {
    asm volatile("s_barrier" ::: "memory");
}

// ws layout (bytes):
//   [0,       589824)  aggb2 [B][half(2)][tap(9)][ch(4)][co(64)][8ci] bf16
//   [589824,  589952)  zero pad (128 B)
//   [1048576, +64MiB)  xT2   [B][q(4)][pix(HW)][16ci] bf16
#define WS_PAD_OFF 589824
#define WS_XT_OFF  1048576

// ---------------------------------------------------------------------------
// Kernel 1 (fused): blocks 0..8191 transpose+convert x -> xT2 bf16;
// blocks 8192..9343 aggregate weights -> aggb2 bf16 + zero pad.
// x reads + xT writes nontemporal: both streams are single-touch for this
// kernel (xT re-read only by a later kernel on other XCDs) — keep them out
// of L2 (round-14 lesson: L2 allocation policy was worth 12.8 us on conv).
// ---------------------------------------------------------------------------
__global__ __launch_bounds__(256) void prep_kernel(
    const float* __restrict__ x,
    const float* __restrict__ att, const float* __restrict__ weight,
    const float* __restrict__ tb, const float* __restrict__ tq,
    const float* __restrict__ tn, const float* __restrict__ tx,
    const float* __restrict__ mb, const float* __restrict__ mq,
    const float* __restrict__ mn, const float* __restrict__ mx,
    unsigned short* __restrict__ aggb, unsigned short* __restrict__ xT)
{
    __shared__ unsigned short tile[64 * 72];   // transpose staging

    int bid = blockIdx.x;
    int t   = threadIdx.x;

    if (bid >= 8192) {                         // ---- weights part ----
        int idx = (bid - 8192) * 256 + t;
        if (idx < 64) aggb[294912 + idx] = 0;  // zero pad region (128 B)
        if (idx >= B_ * 9 * COUT_ * CIN_) return;
        int b    = idx / (9 * COUT_ * CIN_);
        int rem  = idx - b * (9 * COUT_ * CIN_);
        int tap  = rem / (COUT_ * CIN_);
        int rem2 = rem & (COUT_ * CIN_ - 1);
        int co   = rem2 >> 6;
        int ci   = rem2 & 63;
        int r  = (co * CIN_ + ci) * 9 + tap;   // [co][ci][kh][kw]
        int cc = co * CIN_ + ci;
        float a0 = att[b * 10 + 0];
        float a1 = att[b * 10 + 1];
        float a2 = att[b * 10 + 2];
        float val = weight[r]
                  + tb[r] * mb[cc] * a1
                  + tq[r] * mq[cc] * a2
                  + (tn[r] * mn[cc] + tx[r] * mx[cc]) * a0;
        // aggb2[b][half][tap][ch][co][8]: half=ci>>5, ch=(ci>>3)&3, o=ci&7
        int half = ci >> 5, ch = (ci >> 3) & 3, o = ci & 7;
        aggb[((((b * 2 + half) * 9 + tap) * 4 + ch) * 64 + co) * 8 + o] = f2bf(val);
        return;
    }

    // ---- transpose part: tile = 64 pixels x 64 ci of one batch ----
    int b  = bid >> 10;
    int p0 = (bid & 1023) << 6;
    int l  = t & 63;       // pixel lane
    int g  = t >> 6;       // wave -> ci group g*16..+15

    const float* xp = x + (((size_t)(b * CIN_ + g * 16)) << 16) + p0 + l;
    unsigned pk[8];
#pragma unroll
    for (int i = 0; i < 8; ++i) {
        float v0 = __builtin_nontemporal_load(&xp[(size_t)(2 * i) << 16]);
        float v1 = __builtin_nontemporal_load(&xp[(size_t)(2 * i + 1) << 16]);
        pk[i] = (unsigned)f2bf(v0) | ((unsigned)f2bf(v1) << 16);
    }
    *(uint4*)&tile[l * 72 + g * 16]     = make_uint4(pk[0], pk[1], pk[2], pk[3]);
    *(uint4*)&tile[l * 72 + g * 16 + 8] = make_uint4(pk[4], pk[5], pk[6], pk[7]);
    __syncthreads();

    // xT2[b][q][pix][16ci]: write ci-octet c of pixel p0+p at plane q=c>>1.
#pragma unroll
    for (int it = 0; it < 2; ++it) {
        int p = t >> 2;
        int c = (t & 3) + it * 4;              // ci octet 0..7
        uint32x4 v = *(const uint32x4*)&tile[p * 72 + c * 8];
        size_t off = (((size_t)(b * 4 + (c >> 1))) << 20)   // plane, in shorts (65536*16)
                   + (size_t)(p0 + p) * 16 + (c & 1) * 8;
        __builtin_nontemporal_store(v, (uint32x4*)&xT[off]);
    }
}

// ---------------------------------------------------------------------------
// Kernel 2: implicit-GEMM conv, 4-phase (16-ci) double-buffered pipeline.
// Block: 512 thr = 8 waves. Tile: 64 cout x (8 rows x 64 cols), one batch.
// LDS (79.9 KB -> 2 blocks/CU):
//   xlds[2][slot(672)][32B]: B operand. Chunk-XOR f(s)=(s>>1)&1 makes the
//     16B ds_read_b128 tile all 8 bank-quads 8x (conflict-free, any base),
//     while staging lanes cover a contiguous 1024B global span (coalesced).
//   wlds[tap(9)][ch(4)][co(64)][8ci]: A operand, contiguous reads; global
//     source aggb2 is linear in transfer index (fully coalesced).
// Pipeline per phase p: issue stage(p+1) -> vmcnt(newest) -> bar ->
// compute(p) -> bar  (loads stay in flight across compute).
// Epilogue: nontemporal full-128B-line stores (out never re-read; keeps
// xT halo + W lines resident in L2 -> less re-fetch). [round-14: -12.8 us]
// ---------------------------------------------------------------------------
__global__ __launch_bounds__(512, 4) void conv_kernel(
    const unsigned char* __restrict__ wsb,  // d_ws base
    const float* __restrict__ bias,         // [COUT]
    float* __restrict__ out)                // [B][COUT][H][W] fp32
{
    __shared__ __align__(16) unsigned short xlds[2][10752];  // 2 x 21504 B
    __shared__ __align__(16) unsigned short wlds[18432];     // 36864 B

    const int t = threadIdx.x;

    // XCD swizzle: 1024 blocks, xcd = bid&7 = batch.
    int bid = blockIdx.x;
    int bz  = bid & 7;            // batch
    int idx = bid >> 3;           // 0..127
    int ct  = idx >> 5;           // 0..3  col tile
    int rt  = idx & 31;           // 0..31 row tile
    const int x0 = ct * 64;
    const int y0 = rt * 8;

    const int l  = t & 63;
    const int w  = t >> 6;        // wave 0..7 -> output row
    const int lp = l & 31;        // pixel / co lane
    const int lk = l >> 5;        // k-half

    const unsigned char* wbB  = wsb + (size_t)bz * 73728;
    const unsigned char* xTB  = wsb + WS_XT_OFF + (size_t)bz * ((size_t)HW_ * CIN_ * 2);
    const unsigned char* zpad = wsb + WS_PAD_OFF;

    // ---- per-thread staging sources ----
    // X: transfer j = i*512+t (j<1344): slot s=j>>1, chunk ch'=j&1.
    //    LDS[s*32 + ch'*16] holds ci-octet (ch' ^ f(s)), f(s)=(s>>1)&1.
    //    src = xT2[pix(s)]*32 + (ch'^f)*16 (+ q*2MB per phase).
    const unsigned char* xsrc[3];
    bool xval[3];
#pragma unroll
    for (int i = 0; i < 3; ++i) {
        int j   = i * 512 + t;
        int s   = j >> 1;
        int ch  = j & 1;
        int row = s / 66;
        int col = s - row * 66;
        int gy  = y0 + row - 1;
        int gx  = x0 + col - 1;
        bool v  = (s < 660) && ((unsigned)gy < H_) && ((unsigned)gx < W_);
        xval[i] = v;
        int oct = ch ^ ((s >> 1) & 1);
        xsrc[i] = xTB + ((size_t)(gy * W_ + gx)) * 32 + (oct << 4);
    }
    // W: transfer j = i*512+t (j<2304): src = aggb2 + half*36864 + j*16 (linear).
    const unsigned char* wsrc[5];
#pragma unroll
    for (int i = 0; i < 5; ++i)
        wsrc[i] = wbB + (size_t)(i * 512 + t) * 16;

    auto issue_x = [&](unsigned short* buf, int qoff) {
        const unsigned char* s0 = xval[0] ? xsrc[0] + qoff : zpad;
        const unsigned char* s1 = xval[1] ? xsrc[1] + qoff : zpad;
        gload16((char*)buf + t * 16,        s0);
        gload16((char*)buf + 8192 + t * 16, s1);
        if (t < 320) {                                     // waves 0-4 only
            const unsigned char* s2 = xval[2] ? xsrc[2] + qoff : zpad;
            gload16((char*)buf + 16384 + t * 16, s2);
        }
    };
    auto issue_w = [&](int hoff) {
        gload16((char*)wlds + t * 16,         wsrc[0] + hoff);
        gload16((char*)wlds + 8192 + t * 16,  wsrc[1] + hoff);
        gload16((char*)wlds + 16384 + t * 16, wsrc[2] + hoff);
        gload16((char*)wlds + 24576 + t * 16, wsrc[3] + hoff);
        if (t < 256)                                       // waves 0-3 only
            gload16((char*)wlds + 32768 + t * 16, wsrc[4] + hoff);
    };
    // Wait so that only the newest X batch may remain in flight.
    auto waitx = [&]() {
        if (t < 320) { asm volatile("s_waitcnt vmcnt(3)" ::: "memory"); }
        else         { asm volatile("s_waitcnt vmcnt(2)" ::: "memory"); }
    };

    f32x16 acc[2][2];             // [co-group][pixel-group]
#pragma unroll
    for (int i = 0; i < 16; ++i) {
        acc[0][0][i] = 0.f; acc[0][1][i] = 0.f;
        acc[1][0][i] = 0.f; acc[1][1][i] = 0.f;
    }

    const int sB0 = w * 66 + lp;

    // compute one 16-ci phase from buffer `buf`, W k-half h (0=lo,1=hi).
    auto compute = [&](const unsigned short* buf, const int h) {
        const char* Ab = (const char*)wlds + h * 2048 + lk * 1024 + lp * 16;
        __builtin_amdgcn_s_setprio(1);
#pragma unroll
        for (int tap = 0; tap < 9; ++tap) {
            const int kh = tap / 3;
            const int kw = tap - kh * 3;
            short8 a0 = *(const short8*)(Ab + tap * 4096);
            short8 a1 = *(const short8*)(Ab + tap * 4096 + 512);
#pragma unroll
            for (int pb = 0; pb < 2; ++pb) {
                int s    = sB0 + kh * 66 + kw + pb * 32;
                int boff = (s * 32 + (lk << 4)) ^ ((s & 2) << 3);
                short8 bv = *(const short8*)((const char*)buf + boff);
                acc[0][pb] = __builtin_amdgcn_mfma_f32_32x32x16_bf16(a0, bv, acc[0][pb], 0, 0, 0);
                acc[1][pb] = __builtin_amdgcn_mfma_f32_32x32x16_bf16(a1, bv, acc[1][pb], 0, 0, 0);
            }
        }
        __builtin_amdgcn_s_setprio(0);
    };

    // ---- pipeline ----
    issue_w(0);                   // W ci 0-31
    issue_x(xlds[0], 0);          // X q0 (ci 0-15)
    issue_x(xlds[1], 2097152);    // X q1 (ci 16-31)
    waitx();                      // drains W1 + X0; X1 in flight
    bar();
    compute(xlds[0], 0);          // phase 0
    bar();
    issue_x(xlds[0], 4194304);    // X q2 (ci 32-47)
    waitx();                      // drains X1; X2 in flight
    bar();
    compute(xlds[1], 1);          // phase 1
    bar();
    issue_w(36864);               // W ci 32-63 (wlds free now)
    issue_x(xlds[1], 6291456);    // X q3 (ci 48-63)
    waitx();                      // drains X2 + W2; X3 in flight
    bar();
    compute(xlds[0], 0);          // phase 2
    asm volatile("s_waitcnt vmcnt(0)" ::: "memory");   // drain X3
    bar();
    compute(xlds[1], 1);          // phase 3

    // ---- epilogue: bias + nontemporal store (full 128B line segments) ----
    const size_t ob = (size_t)bz * COUT_ * HW_ + (size_t)(y0 + w) * W_ + x0;
#pragma unroll
    for (int cg = 0; cg < 2; ++cg) {
#pragma unroll
        for (int g = 0; g < 16; ++g) {
            int co = cg * 32 + (g & 3) + 8 * (g >> 2) + 4 * lk;
            float bs = bias[co];
            __builtin_nontemporal_store(acc[cg][0][g] + bs,
                &out[ob + (size_t)co * HW_ + lp]);
            __builtin_nontemporal_store(acc[cg][1][g] + bs,
                &out[ob + (size_t)co * HW_ + 32 + lp]);
        }
    }
}

extern "C" void kernel_launch(void* const* d_in, const int* in_sizes, int n_in,
                              void* d_out, int out_size, void* d_ws, size_t ws_size,
                              hipStream_t stream) {
    const float* x      = (const float*)d_in[0];
    const float* att    = (const float*)d_in[1];
    const float* weight = (const float*)d_in[2];
    const float* tb     = (const float*)d_in[3];
    const float* tq     = (const float*)d_in[4];
    const float* tn     = (const float*)d_in[5];
    const float* tx     = (const float*)d_in[6];
    const float* mb     = (const float*)d_in[7];
    const float* mq     = (const float*)d_in[8];
    const float* mn     = (const float*)d_in[9];
    const float* mx     = (const float*)d_in[10];
    const float* bias   = (const float*)d_in[11];

    unsigned short* aggb = (unsigned short*)d_ws;
    unsigned short* xT   = (unsigned short*)((unsigned char*)d_ws + WS_XT_OFF);
    float* outp = (float*)d_out;

    // blocks 0..8191: transpose; 8192..9343: weight aggregation (1152 blocks)
    prep_kernel<<<9344, 256, 0, stream>>>(
        x, att, weight, tb, tq, tn, tx, mb, mq, mn, mx, aggb, xT);

    conv_kernel<<<1024, 512, 0, stream>>>((const unsigned char*)d_ws, bias, outp);
}

// Round 17
// 80.386 us; speedup vs baseline: 1.2502x; 1.2502x over previous
//
#include <hip/hip_runtime.h>

#define B_    8
#define CIN_  64
#define COUT_ 64
#define H_    256
#define W_    256
#define HW_   65536

typedef __attribute__((ext_vector_type(8)))  short short8;    // 8 bf16 = 4 VGPRs
typedef __attribute__((ext_vector_type(16))) float f32x16;

static __device__ __forceinline__ unsigned short f2bf(float f) {
    union { float f; unsigned u; } v; v.f = f;
    unsigned r = (v.u + 0x7FFFu + ((v.u >> 16) & 1u)) >> 16;  // RNE
    return (unsigned short)r;
}

// async global->LDS, 16B per lane. LDS dest = wave-uniform base + lane*16.
static __device__ __forceinline__ void gload16(void* lds, const void* g) {
    __builtin_amdgcn_global_load_lds(
        (const __attribute__((address_space(1))) unsigned int*)g,
        (__attribute__((address_space(3))) unsigned int*)lds, 16, 0, 0);
}

// inline-asm barrier: also a compiler memory fence.
static __device__ __forceinline__ void bar() {
    asm volatile("s_barrier" ::: "memory");
}

// ws layout (bytes):
//   [0,       589824)  aggb2 [B][half(2)][tap(9)][ch(4)][co(64)][8ci] bf16
//   [589824,  589952)  zero pad (128 B)
//   [1048576, +64MiB)  xT2   [B][q(4)][pix(HW)][16ci] bf16
#define WS_PAD_OFF 589824
#define WS_XT_OFF  1048576

// ---------------------------------------------------------------------------
// Kernel 1 (fused): blocks 0..8191 transpose+convert x -> xT2 bf16;
// blocks 8192..9343 aggregate weights -> aggb2 bf16 + zero pad.
// NOTE (round-16 lesson): keep x loads / xT stores as NORMAL cached ops —
// xT is a producer->consumer intermediate re-read by conv; nt-hints here
// cost +20 us. nt is only for never-re-read streams (conv's out).
// ---------------------------------------------------------------------------
__global__ __launch_bounds__(256) void prep_kernel(
    const float* __restrict__ x,
    const float* __restrict__ att, const float* __restrict__ weight,
    const float* __restrict__ tb, const float* __restrict__ tq,
    const float* __restrict__ tn, const float* __restrict__ tx,
    const float* __restrict__ mb, const float* __restrict__ mq,
    const float* __restrict__ mn, const float* __restrict__ mx,
    unsigned short* __restrict__ aggb, unsigned short* __restrict__ xT)
{
    __shared__ unsigned short tile[64 * 72];   // transpose staging

    int bid = blockIdx.x;
    int t   = threadIdx.x;

    if (bid >= 8192) {                         // ---- weights part ----
        int idx = (bid - 8192) * 256 + t;
        if (idx < 64) aggb[294912 + idx] = 0;  // zero pad region (128 B)
        if (idx >= B_ * 9 * COUT_ * CIN_) return;
        int b    = idx / (9 * COUT_ * CIN_);
        int rem  = idx - b * (9 * COUT_ * CIN_);
        int tap  = rem / (COUT_ * CIN_);
        int rem2 = rem & (COUT_ * CIN_ - 1);
        int co   = rem2 >> 6;
        int ci   = rem2 & 63;
        int r  = (co * CIN_ + ci) * 9 + tap;   // [co][ci][kh][kw]
        int cc = co * CIN_ + ci;
        float a0 = att[b * 10 + 0];
        float a1 = att[b * 10 + 1];
        float a2 = att[b * 10 + 2];
        float val = weight[r]
                  + tb[r] * mb[cc] * a1
                  + tq[r] * mq[cc] * a2
                  + (tn[r] * mn[cc] + tx[r] * mx[cc]) * a0;
        // aggb2[b][half][tap][ch][co][8]: half=ci>>5, ch=(ci>>3)&3, o=ci&7
        int half = ci >> 5, ch = (ci >> 3) & 3, o = ci & 7;
        aggb[((((b * 2 + half) * 9 + tap) * 4 + ch) * 64 + co) * 8 + o] = f2bf(val);
        return;
    }

    // ---- transpose part: tile = 64 pixels x 64 ci of one batch ----
    int b  = bid >> 10;
    int p0 = (bid & 1023) << 6;
    int l  = t & 63;       // pixel lane
    int g  = t >> 6;       // wave -> ci group g*16..+15

    const float* xp = x + (((size_t)(b * CIN_ + g * 16)) << 16) + p0 + l;
    unsigned pk[8];
#pragma unroll
    for (int i = 0; i < 8; ++i) {
        float v0 = xp[(size_t)(2 * i) << 16];
        float v1 = xp[(size_t)(2 * i + 1) << 16];
        pk[i] = (unsigned)f2bf(v0) | ((unsigned)f2bf(v1) << 16);
    }
    *(uint4*)&tile[l * 72 + g * 16]     = make_uint4(pk[0], pk[1], pk[2], pk[3]);
    *(uint4*)&tile[l * 72 + g * 16 + 8] = make_uint4(pk[4], pk[5], pk[6], pk[7]);
    __syncthreads();

    // xT2[b][q][pix][16ci]: write ci-octet c of pixel p0+p at plane q=c>>1.
#pragma unroll
    for (int it = 0; it < 2; ++it) {
        int p = t >> 2;
        int c = (t & 3) + it * 4;              // ci octet 0..7
        uint4 v = *(const uint4*)&tile[p * 72 + c * 8];
        size_t off = (((size_t)(b * 4 + (c >> 1))) << 20)   // plane, in shorts (65536*16)
                   + (size_t)(p0 + p) * 16 + (c & 1) * 8;
        *(uint4*)&xT[off] = v;
    }
}

// ---------------------------------------------------------------------------
// Kernel 2: implicit-GEMM conv, 4-phase (16-ci) double-buffered pipeline.
// Block: 512 thr = 8 waves. Tile: 64 cout x (8 rows x 64 cols), one batch.
// LDS (79.9 KB -> 2 blocks/CU):
//   xlds[2][slot(672)][32B]: B operand. Chunk-XOR f(s)=(s>>1)&1 makes the
//     16B ds_read_b128 tile all 8 bank-quads 8x (conflict-free, any base),
//     while staging lanes cover a contiguous 1024B global span (coalesced).
//   wlds[tap(9)][ch(4)][co(64)][8ci]: A operand, contiguous reads; global
//     source aggb2 is linear in transfer index (fully coalesced).
// Pipeline per phase p: issue stage(p+1) -> vmcnt(newest) -> bar ->
// compute(p) -> bar  (loads stay in flight across compute).
// Epilogue: nontemporal full-128B-line stores (out never re-read; keeps
// xT halo + W lines resident in L2 -> less re-fetch). [round-14: -12.8 us]
// ---------------------------------------------------------------------------
__global__ __launch_bounds__(512, 4) void conv_kernel(
    const unsigned char* __restrict__ wsb,  // d_ws base
    const float* __restrict__ bias,         // [COUT]
    float* __restrict__ out)                // [B][COUT][H][W] fp32
{
    __shared__ __align__(16) unsigned short xlds[2][10752];  // 2 x 21504 B
    __shared__ __align__(16) unsigned short wlds[18432];     // 36864 B

    const int t = threadIdx.x;

    // XCD swizzle: 1024 blocks, xcd = bid&7 = batch.
    int bid = blockIdx.x;
    int bz  = bid & 7;            // batch
    int idx = bid >> 3;           // 0..127
    int ct  = idx >> 5;           // 0..3  col tile
    int rt  = idx & 31;           // 0..31 row tile
    const int x0 = ct * 64;
    const int y0 = rt * 8;

    const int l  = t & 63;
    const int w  = t >> 6;        // wave 0..7 -> output row
    const int lp = l & 31;        // pixel / co lane
    const int lk = l >> 5;        // k-half

    const unsigned char* wbB  = wsb + (size_t)bz * 73728;
    const unsigned char* xTB  = wsb + WS_XT_OFF + (size_t)bz * ((size_t)HW_ * CIN_ * 2);
    const unsigned char* zpad = wsb + WS_PAD_OFF;

    // ---- per-thread staging sources ----
    // X: transfer j = i*512+t (j<1344): slot s=j>>1, chunk ch'=j&1.
    //    LDS[s*32 + ch'*16] holds ci-octet (ch' ^ f(s)), f(s)=(s>>1)&1.
    //    src = xT2[pix(s)]*32 + (ch'^f)*16 (+ q*2MB per phase).
    const unsigned char* xsrc[3];
    bool xval[3];
#pragma unroll
    for (int i = 0; i < 3; ++i) {
        int j   = i * 512 + t;
        int s   = j >> 1;
        int ch  = j & 1;
        int row = s / 66;
        int col = s - row * 66;
        int gy  = y0 + row - 1;
        int gx  = x0 + col - 1;
        bool v  = (s < 660) && ((unsigned)gy < H_) && ((unsigned)gx < W_);
        xval[i] = v;
        int oct = ch ^ ((s >> 1) & 1);
        xsrc[i] = xTB + ((size_t)(gy * W_ + gx)) * 32 + (oct << 4);
    }
    // W: transfer j = i*512+t (j<2304): src = aggb2 + half*36864 + j*16 (linear).
    const unsigned char* wsrc[5];
#pragma unroll
    for (int i = 0; i < 5; ++i)
        wsrc[i] = wbB + (size_t)(i * 512 + t) * 16;

    auto issue_x = [&](unsigned short* buf, int qoff) {
        const unsigned char* s0 = xval[0] ? xsrc[0] + qoff : zpad;
        const unsigned char* s1 = xval[1] ? xsrc[1] + qoff : zpad;
        gload16((char*)buf + t * 16,        s0);
        gload16((char*)buf + 8192 + t * 16, s1);
        if (t < 320) {                                     // waves 0-4 only
            const unsigned char* s2 = xval[2] ? xsrc[2] + qoff : zpad;
            gload16((char*)buf + 16384 + t * 16, s2);
        }
    };
    auto issue_w = [&](int hoff) {
        gload16((char*)wlds + t * 16,         wsrc[0] + hoff);
        gload16((char*)wlds + 8192 + t * 16,  wsrc[1] + hoff);
        gload16((char*)wlds + 16384 + t * 16, wsrc[2] + hoff);
        gload16((char*)wlds + 24576 + t * 16, wsrc[3] + hoff);
        if (t < 256)                                       // waves 0-3 only
            gload16((char*)wlds + 32768 + t * 16, wsrc[4] + hoff);
    };
    // Wait so that only the newest X batch may remain in flight.
    auto waitx = [&]() {
        if (t < 320) { asm volatile("s_waitcnt vmcnt(3)" ::: "memory"); }
        else         { asm volatile("s_waitcnt vmcnt(2)" ::: "memory"); }
    };

    f32x16 acc[2][2];             // [co-group][pixel-group]
#pragma unroll
    for (int i = 0; i < 16; ++i) {
        acc[0][0][i] = 0.f; acc[0][1][i] = 0.f;
        acc[1][0][i] = 0.f; acc[1][1][i] = 0.f;
    }

    const int sB0 = w * 66 + lp;

    // compute one 16-ci phase from buffer `buf`, W k-half h (0=lo,1=hi).
    auto compute = [&](const unsigned short* buf, const int h) {
        const char* Ab = (const char*)wlds + h * 2048 + lk * 1024 + lp * 16;
        __builtin_amdgcn_s_setprio(1);
#pragma unroll
        for (int tap = 0; tap < 9; ++tap) {
            const int kh = tap / 3;
            const int kw = tap - kh * 3;
            short8 a0 = *(const short8*)(Ab + tap * 4096);
            short8 a1 = *(const short8*)(Ab + tap * 4096 + 512);
#pragma unroll
            for (int pb = 0; pb < 2; ++pb) {
                int s    = sB0 + kh * 66 + kw + pb * 32;
                int boff = (s * 32 + (lk << 4)) ^ ((s & 2) << 3);
                short8 bv = *(const short8*)((const char*)buf + boff);
                acc[0][pb] = __builtin_amdgcn_mfma_f32_32x32x16_bf16(a0, bv, acc[0][pb], 0, 0, 0);
                acc[1][pb] = __builtin_amdgcn_mfma_f32_32x32x16_bf16(a1, bv, acc[1][pb], 0, 0, 0);
            }
        }
        __builtin_amdgcn_s_setprio(0);
    };

    // ---- pipeline ----
    issue_w(0);                   // W ci 0-31
    issue_x(xlds[0], 0);          // X q0 (ci 0-15)
    issue_x(xlds[1], 2097152);    // X q1 (ci 16-31)
    waitx();                      // drains W1 + X0; X1 in flight
    bar();
    compute(xlds[0], 0);          // phase 0
    bar();
    issue_x(xlds[0], 4194304);    // X q2 (ci 32-47)
    waitx();                      // drains X1; X2 in flight
    bar();
    compute(xlds[1], 1);          // phase 1
    bar();
    issue_w(36864);               // W ci 32-63 (wlds free now)
    issue_x(xlds[1], 6291456);    // X q3 (ci 48-63)
    waitx();                      // drains X2 + W2; X3 in flight
    bar();
    compute(xlds[0], 0);          // phase 2
    asm volatile("s_waitcnt vmcnt(0)" ::: "memory");   // drain X3
    bar();
    compute(xlds[1], 1);          // phase 3

    // ---- epilogue: bias + nontemporal store (full 128B line segments) ----
    const size_t ob = (size_t)bz * COUT_ * HW_ + (size_t)(y0 + w) * W_ + x0;
#pragma unroll
    for (int cg = 0; cg < 2; ++cg) {
#pragma unroll
        for (int g = 0; g < 16; ++g) {
            int co = cg * 32 + (g & 3) + 8 * (g >> 2) + 4 * lk;
            float bs = bias[co];
            __builtin_nontemporal_store(acc[cg][0][g] + bs,
                &out[ob + (size_t)co * HW_ + lp]);
            __builtin_nontemporal_store(acc[cg][1][g] + bs,
                &out[ob + (size_t)co * HW_ + 32 + lp]);
        }
    }
}

extern "C" void kernel_launch(void* const* d_in, const int* in_sizes, int n_in,
                              void* d_out, int out_size, void* d_ws, size_t ws_size,
                              hipStream_t stream) {
    const float* x      = (const float*)d_in[0];
    const float* att    = (const float*)d_in[1];
    const float* weight = (const float*)d_in[2];
    const float* tb     = (const float*)d_in[3];
    const float* tq     = (const float*)d_in[4];
    const float* tn     = (const float*)d_in[5];
    const float* tx     = (const float*)d_in[6];
    const float* mb     = (const float*)d_in[7];
    const float* mq     = (const float*)d_in[8];
    const float* mn     = (const float*)d_in[9];
    const float* mx     = (const float*)d_in[10];
    const float* bias   = (const float*)d_in[11];

    unsigned short* aggb = (unsigned short*)d_ws;
    unsigned short* xT   = (unsigned short*)((unsigned char*)d_ws + WS_XT_OFF);
    float* outp = (float*)d_out;

    // blocks 0..8191: transpose; 8192..9343: weight aggregation (1152 blocks)
    prep_kernel<<<9344, 256, 0, stream>>>(
        x, att, weight, tb, tq, tn, tx, mb, mq, mn, mx, aggb, xT);

    conv_kernel<<<1024, 512, 0, stream>>>((const unsigned char*)d_ws, bias, outp);
}